// Round 2
// baseline (188.160 us; speedup 1.0000x reference)
//
#include <hip/hip_runtime.h>

typedef __bf16 bf16;
typedef __bf16 bf16x8 __attribute__((ext_vector_type(8)));
typedef float f32x4 __attribute__((ext_vector_type(4)));

#define T_LEN   4096
#define D_MODEL 1024
#define QKV_LD  1536
#define VT_LD   4128   // 4096 + 32 pad: last tile's PV chunk over-reads into pad (x0 P)
#define WINDOW  256

// ---------------- prep kernels ----------------

__global__ void cvt_f32_bf16(const float* __restrict__ in, bf16* __restrict__ out, int n) {
    int i = (blockIdx.x * blockDim.x + threadIdx.x) * 8;
    if (i >= n) return;
    float4 a = *(const float4*)(in + i);
    float4 b = *(const float4*)(in + i + 4);
    bf16x8 o;
    o[0] = (bf16)a.x; o[1] = (bf16)a.y; o[2] = (bf16)a.z; o[3] = (bf16)a.w;
    o[4] = (bf16)b.x; o[5] = (bf16)b.y; o[6] = (bf16)b.z; o[7] = (bf16)b.w;
    *(bf16x8*)(out + i) = o;
}

__global__ void concat_bias(const float* __restrict__ bq, const float* __restrict__ bk,
                            const float* __restrict__ bv, float* __restrict__ out) {
    int i = blockIdx.x * blockDim.x + threadIdx.x;   // grid covers exactly 1536
    if (i < 1024)      out[i] = bq[i];
    else if (i < 1280) out[i] = bk[i - 1024];
    else               out[i] = bv[i - 1280];
}

// W (K x N, f32) -> Wt (N x K, bf16)
__global__ void transpose_w(const float* __restrict__ W, bf16* __restrict__ Wt, int K, int N) {
    __shared__ float t[32][33];
    int n0 = blockIdx.x * 32, k0 = blockIdx.y * 32;
    int tx = threadIdx.x & 31, ty = threadIdx.x >> 5;   // ty 0..7
#pragma unroll
    for (int it = 0; it < 4; ++it)
        t[ty + it * 8][tx] = W[(size_t)(k0 + ty + it * 8) * N + n0 + tx];
    __syncthreads();
#pragma unroll
    for (int it = 0; it < 4; ++it)
        Wt[(size_t)(n0 + ty + it * 8) * K + k0 + tx] = (bf16)t[tx][ty + it * 8];
}

// V cols of QKV (T x 1536, cols 1280..1535) -> Vt (256 x VT_LD)
__global__ void transpose_v(const bf16* __restrict__ QKV, bf16* __restrict__ Vt) {
    __shared__ bf16 t[32][33];
    int t0 = blockIdx.x * 32;   // token tile
    int c0 = blockIdx.y * 32;   // v feature tile (0..255)
    int tx = threadIdx.x & 31, ty = threadIdx.x >> 5;
#pragma unroll
    for (int it = 0; it < 4; ++it)
        t[ty + it * 8][tx] = QKV[(size_t)(t0 + ty + it * 8) * QKV_LD + 1280 + c0 + tx];
    __syncthreads();
#pragma unroll
    for (int it = 0; it < 4; ++it)
        Vt[(size_t)(c0 + ty + it * 8) * VT_LD + t0 + tx] = t[tx][ty + it * 8];
}

// ---------------- GEMM: C(MxN) = A(MxK) * Bt(NxK)^T + bias ----------------
// 128x64 tile, BK=32, 4 waves (2x2), wave does 64x32 = 4x2 MFMA tiles.
// Staging: A tile 128 rows x 64 B = 8 KB over 256 thr (32 B each);
//          B tile  64 rows x 64 B = 4 KB over 128 thr (32 B each).

template <bool OUT_BF16>
__global__ __launch_bounds__(256) void gemm_bt(
    const bf16* __restrict__ A, const bf16* __restrict__ Bt,
    const float* __restrict__ bias, void* __restrict__ Cv,
    int M, int N, int K)
{
    __shared__ bf16 As[128][40];   // 80 B rows: 16B aligned, 2-way bank alias only
    __shared__ bf16 Bs[64][40];
    const int m0 = blockIdx.y * 128;
    const int n0 = blockIdx.x * 64;
    const int tid  = threadIdx.x;
    const int wave = tid >> 6, lane = tid & 63;
    const int quad = lane >> 4, l16 = lane & 15;
    const int wm = wave >> 1, wn = wave & 1;

    f32x4 acc[4][2] = {};

    const int arow = tid >> 1, ahalf = (tid & 1) * 16;   // element offset 0 or 16
    const bf16* aptr = A + (size_t)(m0 + arow) * K + ahalf;
    const bf16* bptr = Bt + (size_t)(n0 + arow) * K + ahalf;   // valid only tid<128

    const int nk = K >> 5;
    for (int kt = 0; kt < nk; ++kt) {
        uint4 av0 = *(const uint4*)(aptr + kt * 32);
        uint4 av1 = *(const uint4*)(aptr + kt * 32 + 8);
        uint4 bv0, bv1;
        if (tid < 128) {
            bv0 = *(const uint4*)(bptr + kt * 32);
            bv1 = *(const uint4*)(bptr + kt * 32 + 8);
        }
        __syncthreads();
        *(uint4*)&As[arow][ahalf]     = av0;
        *(uint4*)&As[arow][ahalf + 8] = av1;
        if (tid < 128) {
            *(uint4*)&Bs[arow][ahalf]     = bv0;
            *(uint4*)&Bs[arow][ahalf + 8] = bv1;
        }
        __syncthreads();
        bf16x8 af[4], bfr[2];
#pragma unroll
        for (int i = 0; i < 4; ++i)
            af[i] = *(const bf16x8*)&As[wm * 64 + i * 16 + l16][quad * 8];
#pragma unroll
        for (int j = 0; j < 2; ++j)
            bfr[j] = *(const bf16x8*)&Bs[wn * 32 + j * 16 + l16][quad * 8];
#pragma unroll
        for (int i = 0; i < 4; ++i)
#pragma unroll
            for (int j = 0; j < 2; ++j)
                acc[i][j] = __builtin_amdgcn_mfma_f32_16x16x32_bf16(af[i], bfr[j], acc[i][j], 0, 0, 0);
    }

#pragma unroll
    for (int i = 0; i < 4; ++i)
#pragma unroll
        for (int j = 0; j < 2; ++j) {
            const int col = n0 + wn * 32 + j * 16 + l16;
            const float bb = bias[col];
#pragma unroll
            for (int r = 0; r < 4; ++r) {
                const int row = m0 + wm * 64 + i * 16 + quad * 4 + r;
                const float v = acc[i][j][r] + bb;
                if (OUT_BF16) ((bf16*)Cv)[(size_t)row * N + col] = (bf16)v;
                else          ((float*)Cv)[(size_t)row * N + col] = v;
            }
        }
}

// ---------------- attention: 1 wave per (16-query tile, head) ----------------
// Window <= 272 keys -> 17 S tiles of 16, PV over 9 K-chunks of 32.

__global__ __launch_bounds__(64) void attn_kernel(
    const bf16* __restrict__ QKV, const bf16* __restrict__ Vt, bf16* __restrict__ Oa)
{
    __shared__ bf16 Ps[16][296];   // 592 B rows: 16B aligned, 2-way alias only
    const int q0 = blockIdx.x * 16;
    const int h  = blockIdx.y;
    const int kh = h >> 2;                     // GQA: head h -> kv head h/4
    const int lane = threadIdx.x;
    const int quad = lane >> 4, l16 = lane & 15;
    const float slope = exp2f(-0.5f * (float)(h + 1));   // NH=16 ALiBi slopes
    const int lo = (q0 >= 256) ? (q0 - 256) : 0;          // 16-aligned window start

    // Q A-fragments (k-chunks 0 and 32 of HD=64)
    const bf16* qp = QKV + (size_t)(q0 + l16) * QKV_LD + h * 64 + quad * 8;
    bf16x8 qf0 = *(const bf16x8*)qp;
    bf16x8 qf1 = *(const bf16x8*)(qp + 32);

    // S = Q K^T : 17 tiles of 16 keys, fully unrolled so s[] stays in VGPRs
    f32x4 s[17];
#pragma unroll
    for (int t = 0; t < 17; ++t) {
        const bf16* kp = QKV + (size_t)(lo + t * 16 + l16) * QKV_LD + D_MODEL + kh * 64 + quad * 8;
        bf16x8 kf0 = *(const bf16x8*)kp;
        bf16x8 kf1 = *(const bf16x8*)(kp + 32);
        f32x4 a = {};
        a = __builtin_amdgcn_mfma_f32_16x16x32_bf16(qf0, kf0, a, 0, 0, 0);
        a = __builtin_amdgcn_mfma_f32_16x16x32_bf16(qf1, kf1, a, 0, 0, 0);
        s[t] = a;
    }

    // masked ALiBi softmax; lane holds rows quad*4+r at col l16 of each tile
    float rinv[4];
#pragma unroll
    for (int r = 0; r < 4; ++r) {
        const int row = q0 + quad * 4 + r;
        float mx = -1e30f;
#pragma unroll
        for (int t = 0; t < 17; ++t) {
            const int key = lo + t * 16 + l16;
            float v = s[t][r] * 0.125f - slope * (float)(row - key);
            const bool ok = (key <= row) && (key > row - WINDOW);
            v = ok ? v : -1e30f;
            s[t][r] = v;
            mx = fmaxf(mx, v);
        }
#pragma unroll
        for (int d = 1; d < 16; d <<= 1) mx = fmaxf(mx, __shfl_xor(mx, d));
        float sum = 0.f;
#pragma unroll
        for (int t = 0; t < 17; ++t) {
            float p = __expf(s[t][r] - mx);
            s[t][r] = p;
            sum += p;
        }
#pragma unroll
        for (int d = 1; d < 16; d <<= 1) sum += __shfl_xor(sum, d);
        rinv[r] = 1.f / sum;
    }

    // zero pad cols [272,288) (PV reads 288 cols)
    {
        int idx = lane;
#pragma unroll
        for (int it = 0; it < 4; ++it) {
            Ps[(idx >> 4) & 15][272 + (idx & 15)] = (bf16)0.f;
            idx += 64;
        }
    }
    // P: C-layout regs -> LDS -> A-layout frags
#pragma unroll
    for (int t = 0; t < 17; ++t)
#pragma unroll
        for (int r = 0; r < 4; ++r)
            Ps[quad * 4 + r][t * 16 + l16] = (bf16)(s[t][r] * rinv[r]);
    __syncthreads();

    // O = P V : V B-frags straight from global Vt (contiguous along keys)
    f32x4 o[4] = {};
#pragma unroll
    for (int c = 0; c < 9; ++c) {
        bf16x8 pf = *(const bf16x8*)&Ps[l16][c * 32 + quad * 8];
#pragma unroll
        for (int j = 0; j < 4; ++j) {
            const bf16* vp = Vt + (size_t)(kh * 64 + j * 16 + l16) * VT_LD + lo + c * 32 + quad * 8;
            bf16x8 vf = *(const bf16x8*)vp;
            o[j] = __builtin_amdgcn_mfma_f32_16x16x32_bf16(pf, vf, o[j], 0, 0, 0);
        }
    }

#pragma unroll
    for (int j = 0; j < 4; ++j)
#pragma unroll
        for (int r = 0; r < 4; ++r)
            Oa[(size_t)(q0 + quad * 4 + r) * D_MODEL + h * 64 + j * 16 + l16] = (bf16)o[j][r];
}

// ---------------- launch ----------------

extern "C" void kernel_launch(void* const* d_in, const int* in_sizes, int n_in,
                              void* d_out, int out_size, void* d_ws, size_t ws_size,
                              hipStream_t stream) {
    const float* x  = (const float*)d_in[0];
    const float* Wq = (const float*)d_in[1];
    const float* bq = (const float*)d_in[2];
    const float* Wk = (const float*)d_in[3];
    const float* bk = (const float*)d_in[4];
    const float* Wv = (const float*)d_in[5];
    const float* bv = (const float*)d_in[6];
    const float* Wo = (const float*)d_in[7];
    const float* bo = (const float*)d_in[8];
    float* out = (float*)d_out;

    char* ws = (char*)d_ws;
    bf16*  xb    = (bf16*)(ws);                    // 4096x1024 bf16   (8 MB)
    bf16*  WtQKV = (bf16*)(ws + 8388608);          // 1536x1024 bf16   (3 MB)
    bf16*  WtO   = (bf16*)(ws + 11534336);         // 1024x1024 bf16   (2 MB)
    float* biasQ = (float*)(ws + 13631488);        // 1536 f32
    bf16*  QKV   = (bf16*)(ws + 13637632);         // 4096x1536 bf16   (12 MB)
    bf16*  Vt    = (bf16*)(ws + 26220544);         // 256xVT_LD bf16   (~2 MB)
    bf16*  AO    = (bf16*)(ws + 28334080);         // 4096x1024 bf16   (8 MB) -> end ~35 MB

    cvt_f32_bf16<<<2048, 256, 0, stream>>>(x, xb, 4096 * 1024);
    concat_bias<<<6, 256, 0, stream>>>(bq, bk, bv, biasQ);
    transpose_w<<<dim3(32, 32), 256, 0, stream>>>(Wq, WtQKV, 1024, 1024);
    transpose_w<<<dim3(8, 32), 256, 0, stream>>>(Wk, WtQKV + (size_t)1024 * 1024, 1024, 256);
    transpose_w<<<dim3(8, 32), 256, 0, stream>>>(Wv, WtQKV + (size_t)1280 * 1024, 1024, 256);
    transpose_w<<<dim3(32, 32), 256, 0, stream>>>(Wo, WtO, 1024, 1024);

    gemm_bt<true><<<dim3(24, 32), 256, 0, stream>>>(xb, WtQKV, biasQ, QKV, 4096, 1536, 1024);
    transpose_v<<<dim3(128, 8), 256, 0, stream>>>(QKV, Vt);
    attn_kernel<<<dim3(256, 16), 64, 0, stream>>>(QKV, Vt, AO);
    gemm_bt<false><<<dim3(16, 32), 256, 0, stream>>>(AO, WtO, bo, out, 4096, 1024, 1024);
}